// Round 3
// baseline (486.818 us; speedup 1.0000x reference)
//
#include <hip/hip_runtime.h>

// 192^3 FDTD, FUSED v3: occupancy-focused. step1 (E->H) on tile+halo -> LDS,
// step2 (H->E) from LDS. Each H2 field is stored in LDS only where phase 2
// reads it: sHx has no x-halo, sHy no y-halo, sHz no z-halo. Tile 8x8x16.
// LDS = 25.9 KB -> 6 blocks/CU (24 waves, vs 3 blocks/12 waves in v2).
// All global I/O float4. Central differences only on the strict interior of
// all three dims; boundary points get zero curl (H2=H, E2=coefE*E there).

#define NXD 192
#define NYD 192
#define NZD 192

static constexpr int   N3    = NXD * NYD * NZD;   // 7,077,888
static constexpr float DTc   = 1e-12f;
static constexpr float INV2D = 500.0f;            // 1/(2*1e-3)

// tile geometry: 8 x 8 x 16 interior cells, 256 threads
static constexpr int TX = 8, TY = 8, TZ = 16;
static constexpr int HXT = 10, HYT = 10;          // halo extents in x,y
static constexpr int ZCH = 6;                     // halo z chunks (24 floats)
static constexpr int NCH = HXT * HYT * ZCH;       // 600 halo chunk tasks

// LDS layouts (floats). Row strides chosen so 8 consecutive y-rows map to
// distinct bank offsets (28*r%32 and 20*r%32 cycle through 8 values).
static constexpr int SHX_X = 280, SHX_Y = 28;     // sHx [8][10][28]
static constexpr int SHY_X = 224, SHY_Y = 28;     // sHy [10][8][28]
static constexpr int SHZ_X = 200, SHZ_Y = 20;     // sHz [10][10][20]

static constexpr int NBX = NXD / TX, NBY = NYD / TY, NBZ = NZD / TZ; // 24,24,12
static constexpr int NBLK = NBX * NBY * NBZ;      // 6912 (%8==0)

__device__ __forceinline__ int clampi(int v, int lo, int hi) {
    return v < lo ? lo : (v > hi ? hi : v);
}

__global__ __launch_bounds__(256, 6) void fdtd_fused(
    const float* __restrict__ Ex, const float* __restrict__ Ey, const float* __restrict__ Ez,
    const float* __restrict__ Hx, const float* __restrict__ Hy, const float* __restrict__ Hz,
    const float* __restrict__ eps, const float* __restrict__ mu, const float* __restrict__ sigma,
    float* __restrict__ Ex2, float* __restrict__ Ey2, float* __restrict__ Ez2,
    float* __restrict__ Hx2, float* __restrict__ Hy2, float* __restrict__ Hz2)
{
    __shared__ float sHx[8 * 10 * 28];   // 8960 B
    __shared__ float sHy[10 * 8 * 28];   // 8960 B
    __shared__ float sHz[10 * 10 * 20];  // 8000 B

    // XCD-bijective swizzle (6912 % 8 == 0)
    int bid = blockIdx.x;
    int swz = (bid & 7) * (NBLK / 8) + (bid >> 3);
    int bz = swz % NBZ;
    int t0 = swz / NBZ;
    int by = t0 % NBY;
    int bx = t0 / NBY;
    int ox = bx * TX, oy = by * TY, oz = bz * TZ;

    int tid = threadIdx.x;

    // ---------------- phase 1: H2 on tile + halo -> LDS (float4 chunks) ----
    #pragma unroll
    for (int it = 0; it < 3; ++it) {
        int h = tid + it * 256;
        if (h < NCH) {
            int cz = h % ZCH;          // 0..5
            int tt = h / ZCH;
            int hy = tt % HYT;         // 0..9
            int hx = tt / HYT;         // 0..9

            int gi = ox + hx - 1;
            int gj = oy + hy - 1;
            int kb = oz + cz * 4 - 4;              // true chunk base (may be OOB)

            int gic  = clampi(gi,     0, NXD - 1);
            int gjc  = clampi(gj,     0, NYD - 1);
            int gipc = clampi(gi + 1, 0, NXD - 1);
            int gimc = clampi(gi - 1, 0, NXD - 1);
            int gjpc = clampi(gj + 1, 0, NYD - 1);
            int gjmc = clampi(gj - 1, 0, NYD - 1);
            int kbc  = clampi(kb,     0, NZD - 4); // float4-aligned, in-bounds
            int km1  = clampi(kb - 1, 0, NZD - 1);
            int kp4  = clampi(kb + 4, 0, NZD - 1);

            int rowC  = (gic  * NYD + gjc ) * NZD;
            int rowXp = (gipc * NYD + gjc ) * NZD;
            int rowXm = (gimc * NYD + gjc ) * NZD;
            int rowYp = (gic  * NYD + gjpc) * NZD;
            int rowYm = (gic  * NYD + gjmc) * NZD;

            float4 ezYp = *(const float4*)(Ez + rowYp + kbc);
            float4 ezYm = *(const float4*)(Ez + rowYm + kbc);
            float4 exYp = *(const float4*)(Ex + rowYp + kbc);
            float4 exYm = *(const float4*)(Ex + rowYm + kbc);
            float4 eyXp = *(const float4*)(Ey + rowXp + kbc);
            float4 eyXm = *(const float4*)(Ey + rowXm + kbc);
            float4 ezXp = *(const float4*)(Ez + rowXp + kbc);
            float4 ezXm = *(const float4*)(Ez + rowXm + kbc);
            float4 eyC  = *(const float4*)(Ey + rowC + kbc);
            float4 exC  = *(const float4*)(Ex + rowC + kbc);
            float  ey_m1 = Ey[rowC + km1], ey_p4 = Ey[rowC + kp4];
            float  ex_m1 = Ex[rowC + km1], ex_p4 = Ex[rowC + kp4];
            float4 hxC = *(const float4*)(Hx + rowC + kbc);
            float4 hyC = *(const float4*)(Hy + rowC + kbc);
            float4 hzC = *(const float4*)(Hz + rowC + kbc);
            float4 muC = *(const float4*)(mu + rowC + kbc);

            const float* ezYpf = (const float*)&ezYp; const float* ezYmf = (const float*)&ezYm;
            const float* exYpf = (const float*)&exYp; const float* exYmf = (const float*)&exYm;
            const float* eyXpf = (const float*)&eyXp; const float* eyXmf = (const float*)&eyXm;
            const float* ezXpf = (const float*)&ezXp; const float* ezXmf = (const float*)&ezXm;
            const float* eyCf  = (const float*)&eyC;  const float* exCf  = (const float*)&exC;
            const float* hxCf  = (const float*)&hxC;  const float* hyCf  = (const float*)&hyC;
            const float* hzCf  = (const float*)&hzC;  const float* muCf  = (const float*)&muC;

            float4 vx, vy, vz;
            float* vxf = (float*)&vx; float* vyf = (float*)&vy; float* vzf = (float*)&vz;

            bool xyok = (gi >= 1) && (gi <= NXD - 2) && (gj >= 1) && (gj <= NYD - 2);
            #pragma unroll
            for (int e = 0; e < 4; ++e) {
                int ke = kb + e;
                bool valid = xyok && (ke >= 1) && (ke <= NZD - 2);
                float eyzm = (e == 0) ? ey_m1 : eyCf[e - 1];
                float eyzp = (e == 3) ? ey_p4 : eyCf[e + 1];
                float exzm = (e == 0) ? ex_m1 : exCf[e - 1];
                float exzp = (e == 3) ? ex_p4 : exCf[e + 1];
                float cx = valid ? ((ezYpf[e] - ezYmf[e]) - (eyzp - eyzm)) * INV2D : 0.0f;
                float cy = valid ? ((exzp - exzm) - (ezXpf[e] - ezXmf[e])) * INV2D : 0.0f;
                float cc = valid ? ((eyXpf[e] - eyXmf[e]) - (exYpf[e] - exYmf[e])) * INV2D : 0.0f;
                float f = DTc / muCf[e];
                vxf[e] = hxCf[e] - f * cx;
                vyf[e] = hyCf[e] - f * cy;
                vzf[e] = hzCf[e] - f * cc;
            }

            // LDS stores: each field only where phase 2 reads it
            if (hx >= 1 && hx <= 8)
                *(float4*)(sHx + (hx - 1) * SHX_X + hy * SHX_Y + cz * 4) = vx;
            if (hy >= 1 && hy <= 8)
                *(float4*)(sHy + hx * SHY_X + (hy - 1) * SHY_Y + cz * 4) = vy;
            if (cz >= 1 && cz <= 4)
                *(float4*)(sHz + hx * SHZ_X + hy * SHZ_Y + (cz - 1) * 4) = vz;

            // tile chunks: store H2 outputs directly from registers
            if (hx >= 1 && hx <= 8 && hy >= 1 && hy <= 8 && cz >= 1 && cz <= 4) {
                int gidx = rowC + kb;  // coords valid & unclamped here
                *(float4*)(Hx2 + gidx) = vx;
                *(float4*)(Hy2 + gidx) = vy;
                *(float4*)(Hz2 + gidx) = vz;
            }
        }
    }

    __syncthreads();

    // ---------------- phase 2: curl(H2) from LDS, E-update (float4) --------
    {
        int zc = tid & 3;            // 0..3
        int iy = (tid >> 2) & 7;     // 0..7
        int ix = tid >> 5;           // 0..7
        int gi = ox + ix, gj = oy + iy;
        int k0 = oz + zc * 4;
        int gidx = (gi * NYD + gj) * NZD + k0;

        // global loads first: hide under the LDS reads below
        float4 exC  = *(const float4*)(Ex + gidx);
        float4 eyC  = *(const float4*)(Ey + gidx);
        float4 ezC  = *(const float4*)(Ez + gidx);
        float4 epsC = *(const float4*)(eps + gidx);
        float4 sigC = *(const float4*)(sigma + gidx);

        int lx = ix * SHX_X + (iy + 1) * SHX_Y + zc * 4 + 4;   // sHx [ix][iy+1][z+4]
        int ly = (ix + 1) * SHY_X + iy * SHY_Y + zc * 4 + 4;   // sHy [ix+1][iy][z+4]
        int lz = (ix + 1) * SHZ_X + (iy + 1) * SHZ_Y + zc * 4; // sHz [ix+1][iy+1][z]

        float4 hzYp = *(const float4*)(sHz + lz + SHZ_Y);
        float4 hzYm = *(const float4*)(sHz + lz - SHZ_Y);
        float4 hzXp = *(const float4*)(sHz + lz + SHZ_X);
        float4 hzXm = *(const float4*)(sHz + lz - SHZ_X);
        float4 hxYp = *(const float4*)(sHx + lx + SHX_Y);
        float4 hxYm = *(const float4*)(sHx + lx - SHX_Y);
        float4 hyXp = *(const float4*)(sHy + ly + SHY_X);
        float4 hyXm = *(const float4*)(sHy + ly - SHY_X);
        float4 hyCv = *(const float4*)(sHy + ly);
        float4 hxCv = *(const float4*)(sHx + lx);
        float  hy_m1 = sHy[ly - 1], hy_p4 = sHy[ly + 4];
        float  hx_m1 = sHx[lx - 1], hx_p4 = sHx[lx + 4];

        const float* hzYpf = (const float*)&hzYp; const float* hzYmf = (const float*)&hzYm;
        const float* hzXpf = (const float*)&hzXp; const float* hzXmf = (const float*)&hzXm;
        const float* hxYpf = (const float*)&hxYp; const float* hxYmf = (const float*)&hxYm;
        const float* hyXpf = (const float*)&hyXp; const float* hyXmf = (const float*)&hyXm;
        const float* hyCf  = (const float*)&hyCv; const float* hxCf  = (const float*)&hxCv;
        const float* exCf  = (const float*)&exC;  const float* eyCf  = (const float*)&eyC;
        const float* ezCf  = (const float*)&ezC;
        const float* epsf  = (const float*)&epsC; const float* sigf  = (const float*)&sigC;

        float4 ex2, ey2, ez2;
        float* ex2f = (float*)&ex2; float* ey2f = (float*)&ey2; float* ez2f = (float*)&ez2;

        bool xyok = (gi >= 1) && (gi <= NXD - 2) && (gj >= 1) && (gj <= NYD - 2);
        #pragma unroll
        for (int e = 0; e < 4; ++e) {
            int ke = k0 + e;
            bool valid = xyok && (ke >= 1) && (ke <= NZD - 2);
            float hyzm = (e == 0) ? hy_m1 : hyCf[e - 1];
            float hyzp = (e == 3) ? hy_p4 : hyCf[e + 1];
            float hxzm = (e == 0) ? hx_m1 : hxCf[e - 1];
            float hxzp = (e == 3) ? hx_p4 : hxCf[e + 1];
            float cx = valid ? ((hzYpf[e] - hzYmf[e]) - (hyzp - hyzm)) * INV2D : 0.0f;
            float cy = valid ? ((hxzp - hxzm) - (hzXpf[e] - hzXmf[e])) * INV2D : 0.0f;
            float cc = valid ? ((hyXpf[e] - hyXmf[e]) - (hxYpf[e] - hxYmf[e])) * INV2D : 0.0f;

            float ee = epsf[e];
            float ss = sigf[e];
            float half_sdt_over_e = ss * DTc / (2.0f * ee);
            float Ap = 1.0f + half_sdt_over_e;
            float Am = 1.0f - half_sdt_over_e;
            float coefE = Am / Ap;
            float coefC = DTc / (ee * Ap);
            ex2f[e] = coefE * exCf[e] + coefC * cx;
            ey2f[e] = coefE * eyCf[e] + coefC * cy;
            ez2f[e] = coefE * ezCf[e] + coefC * cc;
        }

        *(float4*)(Ex2 + gidx) = ex2;
        *(float4*)(Ey2 + gidx) = ey2;
        *(float4*)(Ez2 + gidx) = ez2;
    }
}

extern "C" void kernel_launch(void* const* d_in, const int* in_sizes, int n_in,
                              void* d_out, int out_size, void* d_ws, size_t ws_size,
                              hipStream_t stream)
{
    // setup_inputs order: Ex, Ey, Ez, Hx, Hy, Hz, eps, mu, sigma
    const float* Ex    = (const float*)d_in[0];
    const float* Ey    = (const float*)d_in[1];
    const float* Ez    = (const float*)d_in[2];
    const float* Hx    = (const float*)d_in[3];
    const float* Hy    = (const float*)d_in[4];
    const float* Hz    = (const float*)d_in[5];
    const float* eps   = (const float*)d_in[6];
    const float* mu    = (const float*)d_in[7];
    const float* sigma = (const float*)d_in[8];

    // outputs concatenated flat in return order: ex2, ey2, ez2, hx2, hy2, hz2
    float* out = (float*)d_out;
    float* Ex2 = out + 0 * (size_t)N3;
    float* Ey2 = out + 1 * (size_t)N3;
    float* Ez2 = out + 2 * (size_t)N3;
    float* Hx2 = out + 3 * (size_t)N3;
    float* Hy2 = out + 4 * (size_t)N3;
    float* Hz2 = out + 5 * (size_t)N3;

    fdtd_fused<<<NBLK, 256, 0, stream>>>(Ex, Ey, Ez, Hx, Hy, Hz, eps, mu, sigma,
                                         Ex2, Ey2, Ez2, Hx2, Hy2, Hz2);
}

// Round 5
// 377.550 us; speedup vs baseline: 1.2894x; 1.2894x over previous
//
#include <hip/hip_runtime.h>

// 192^3 FDTD, two-pass STREAMING + float4 vectorization (round 5 = round 4
// with the nontemporal-store type fixed: the builtin needs a native clang
// ext_vector type, not HIP_vector_type).
//
// Empirics from rounds 1-3: fused LDS-tile versions (228/202/248 us) never
// beat the scalar two-pass baseline (~141 us combined kernel time) -- the
// barrier + scattered halo gather costs more than the extra HBM round-trip
// of the intermediate H2. So: keep the streaming structure, cut instruction
// count ~3x by processing a float4 z-chunk per thread.
//
// Coalescing: thread t -> chunk idx4 = bid*256+t; lanes 0..47 cover one full
// z-row contiguously (768 B), no LDS, no barrier, full occupancy.
// Boundaries: central differences only on the strict interior of all three
// dims; clamped addresses + per-element mask give zero curl there
// (H2=H, E2=coefE*E), identical math to the verified kernels.

#define NXD 192
#define NYD 192
#define NZD 192

static constexpr int   N3     = NXD * NYD * NZD;   // 7,077,888
static constexpr int   NCHUNK = N3 / 4;            // 1,769,472
static constexpr float DTc    = 1e-12f;
static constexpr float INV2D  = 500.0f;            // 1/(2*1e-3)

static constexpr int KC = NZD / 4;                 // 48 chunks per z-row

typedef float vf4 __attribute__((ext_vector_type(4)));  // native vec for builtins

__device__ __forceinline__ int clampi(int v, int lo, int hi) {
    return v < lo ? lo : (v > hi ? hi : v);
}

__global__ __launch_bounds__(256) void fdtd_step1(
    const float* __restrict__ Ex, const float* __restrict__ Ey, const float* __restrict__ Ez,
    const float* __restrict__ Hx, const float* __restrict__ Hy, const float* __restrict__ Hz,
    const float* __restrict__ mu,
    float* __restrict__ Hx2, float* __restrict__ Hy2, float* __restrict__ Hz2)
{
    int idx4 = blockIdx.x * blockDim.x + threadIdx.x;
    if (idx4 >= NCHUNK) return;

    int kc = idx4 % KC;
    int t  = idx4 / KC;
    int j  = t % NYD;
    int i  = t / NYD;
    int k0 = kc * 4;

    int ip = clampi(i + 1, 0, NXD - 1);
    int im = clampi(i - 1, 0, NXD - 1);
    int jp = clampi(j + 1, 0, NYD - 1);
    int jm = clampi(j - 1, 0, NYD - 1);
    int km1 = (k0 > 0) ? k0 - 1 : 0;               // only consumed when masked-valid
    int kp4 = (k0 < NZD - 4) ? k0 + 4 : NZD - 1;

    int rowC  = (i  * NYD + j ) * NZD;
    int rowXp = (ip * NYD + j ) * NZD;
    int rowXm = (im * NYD + j ) * NZD;
    int rowYp = (i  * NYD + jp) * NZD;
    int rowYm = (i  * NYD + jm) * NZD;

    // y-stencil
    vf4 ezYp = *(const vf4*)(Ez + rowYp + k0);
    vf4 ezYm = *(const vf4*)(Ez + rowYm + k0);
    vf4 exYp = *(const vf4*)(Ex + rowYp + k0);
    vf4 exYm = *(const vf4*)(Ex + rowYm + k0);
    // x-stencil
    vf4 eyXp = *(const vf4*)(Ey + rowXp + k0);
    vf4 eyXm = *(const vf4*)(Ey + rowXm + k0);
    vf4 ezXp = *(const vf4*)(Ez + rowXp + k0);
    vf4 ezXm = *(const vf4*)(Ez + rowXm + k0);
    // z-stencil (center chunk + edge scalars)
    vf4 eyC  = *(const vf4*)(Ey + rowC + k0);
    vf4 exC  = *(const vf4*)(Ex + rowC + k0);
    float ey_m1 = Ey[rowC + km1], ey_p4 = Ey[rowC + kp4];
    float ex_m1 = Ex[rowC + km1], ex_p4 = Ex[rowC + kp4];
    // update terms
    vf4 hxC = *(const vf4*)(Hx + rowC + k0);
    vf4 hyC = *(const vf4*)(Hy + rowC + k0);
    vf4 hzC = *(const vf4*)(Hz + rowC + k0);
    vf4 muC = *(const vf4*)(mu + rowC + k0);

    vf4 vx, vy, vz;

    bool xyok = (i >= 1) && (i <= NXD - 2) && (j >= 1) && (j <= NYD - 2);
    #pragma unroll
    for (int e = 0; e < 4; ++e) {
        int ke = k0 + e;
        bool valid = xyok && (ke >= 1) && (ke <= NZD - 2);
        float eyzm = (e == 0) ? ey_m1 : eyC[e - 1];
        float eyzp = (e == 3) ? ey_p4 : eyC[e + 1];
        float exzm = (e == 0) ? ex_m1 : exC[e - 1];
        float exzp = (e == 3) ? ex_p4 : exC[e + 1];
        float cx = valid ? ((ezYp[e] - ezYm[e]) - (eyzp - eyzm)) * INV2D : 0.0f;
        float cy = valid ? ((exzp - exzm) - (ezXp[e] - ezXm[e])) * INV2D : 0.0f;
        float cz = valid ? ((eyXp[e] - eyXm[e]) - (exYp[e] - exYm[e])) * INV2D : 0.0f;
        float f = DTc / muC[e];
        vx[e] = hxC[e] - f * cx;
        vy[e] = hyC[e] - f * cy;
        vz[e] = hzC[e] - f * cz;
    }

    // H2 is re-read by step2: keep cached (normal stores).
    *(vf4*)(Hx2 + rowC + k0) = vx;
    *(vf4*)(Hy2 + rowC + k0) = vy;
    *(vf4*)(Hz2 + rowC + k0) = vz;
}

__global__ __launch_bounds__(256) void fdtd_step2(
    const float* __restrict__ Ex, const float* __restrict__ Ey, const float* __restrict__ Ez,
    const float* __restrict__ Hx2, const float* __restrict__ Hy2, const float* __restrict__ Hz2,
    const float* __restrict__ eps, const float* __restrict__ sigma,
    float* __restrict__ Ex2, float* __restrict__ Ey2, float* __restrict__ Ez2)
{
    int idx4 = blockIdx.x * blockDim.x + threadIdx.x;
    if (idx4 >= NCHUNK) return;

    int kc = idx4 % KC;
    int t  = idx4 / KC;
    int j  = t % NYD;
    int i  = t / NYD;
    int k0 = kc * 4;

    int ip = clampi(i + 1, 0, NXD - 1);
    int im = clampi(i - 1, 0, NXD - 1);
    int jp = clampi(j + 1, 0, NYD - 1);
    int jm = clampi(j - 1, 0, NYD - 1);
    int km1 = (k0 > 0) ? k0 - 1 : 0;
    int kp4 = (k0 < NZD - 4) ? k0 + 4 : NZD - 1;

    int rowC  = (i  * NYD + j ) * NZD;
    int rowXp = (ip * NYD + j ) * NZD;
    int rowXm = (im * NYD + j ) * NZD;
    int rowYp = (i  * NYD + jp) * NZD;
    int rowYm = (i  * NYD + jm) * NZD;

    // y-stencil
    vf4 hzYp = *(const vf4*)(Hz2 + rowYp + k0);
    vf4 hzYm = *(const vf4*)(Hz2 + rowYm + k0);
    vf4 hxYp = *(const vf4*)(Hx2 + rowYp + k0);
    vf4 hxYm = *(const vf4*)(Hx2 + rowYm + k0);
    // x-stencil
    vf4 hyXp = *(const vf4*)(Hy2 + rowXp + k0);
    vf4 hyXm = *(const vf4*)(Hy2 + rowXm + k0);
    vf4 hzXp = *(const vf4*)(Hz2 + rowXp + k0);
    vf4 hzXm = *(const vf4*)(Hz2 + rowXm + k0);
    // z-stencil
    vf4 hyC  = *(const vf4*)(Hy2 + rowC + k0);
    vf4 hxC  = *(const vf4*)(Hx2 + rowC + k0);
    float hy_m1 = Hy2[rowC + km1], hy_p4 = Hy2[rowC + kp4];
    float hx_m1 = Hx2[rowC + km1], hx_p4 = Hx2[rowC + kp4];
    // update terms
    vf4 exC  = *(const vf4*)(Ex + rowC + k0);
    vf4 eyC  = *(const vf4*)(Ey + rowC + k0);
    vf4 ezC  = *(const vf4*)(Ez + rowC + k0);
    vf4 epsC = *(const vf4*)(eps + rowC + k0);
    vf4 sigC = *(const vf4*)(sigma + rowC + k0);

    vf4 ex2, ey2, ez2;

    bool xyok = (i >= 1) && (i <= NXD - 2) && (j >= 1) && (j <= NYD - 2);
    #pragma unroll
    for (int e = 0; e < 4; ++e) {
        int ke = k0 + e;
        bool valid = xyok && (ke >= 1) && (ke <= NZD - 2);
        float hyzm = (e == 0) ? hy_m1 : hyC[e - 1];
        float hyzp = (e == 3) ? hy_p4 : hyC[e + 1];
        float hxzm = (e == 0) ? hx_m1 : hxC[e - 1];
        float hxzp = (e == 3) ? hx_p4 : hxC[e + 1];
        float cx = valid ? ((hzYp[e] - hzYm[e]) - (hyzp - hyzm)) * INV2D : 0.0f;
        float cy = valid ? ((hxzp - hxzm) - (hzXp[e] - hzXm[e])) * INV2D : 0.0f;
        float cz = valid ? ((hyXp[e] - hyXm[e]) - (hxYp[e] - hxYm[e])) * INV2D : 0.0f;

        float ee = epsC[e];
        float ss = sigC[e];
        float half_sdt_over_e = ss * DTc / (2.0f * ee);
        float Ap = 1.0f + half_sdt_over_e;
        float Am = 1.0f - half_sdt_over_e;
        float coefE = Am / Ap;
        float coefC = DTc / (ee * Ap);
        ex2[e] = coefE * exC[e] + coefC * cx;
        ey2[e] = coefE * eyC[e] + coefC * cy;
        ez2[e] = coefE * ezC[e] + coefC * cz;
    }

    // E2 is never re-read: nontemporal stores keep L2/L3 for the input streams.
    __builtin_nontemporal_store(ex2, (vf4*)(Ex2 + rowC + k0));
    __builtin_nontemporal_store(ey2, (vf4*)(Ey2 + rowC + k0));
    __builtin_nontemporal_store(ez2, (vf4*)(Ez2 + rowC + k0));
}

extern "C" void kernel_launch(void* const* d_in, const int* in_sizes, int n_in,
                              void* d_out, int out_size, void* d_ws, size_t ws_size,
                              hipStream_t stream)
{
    // setup_inputs order: Ex, Ey, Ez, Hx, Hy, Hz, eps, mu, sigma
    const float* Ex    = (const float*)d_in[0];
    const float* Ey    = (const float*)d_in[1];
    const float* Ez    = (const float*)d_in[2];
    const float* Hx    = (const float*)d_in[3];
    const float* Hy    = (const float*)d_in[4];
    const float* Hz    = (const float*)d_in[5];
    const float* eps   = (const float*)d_in[6];
    const float* mu    = (const float*)d_in[7];
    const float* sigma = (const float*)d_in[8];

    // outputs concatenated flat in return order: ex2, ey2, ez2, hx2, hy2, hz2
    float* out = (float*)d_out;
    float* Ex2 = out + 0 * (size_t)N3;
    float* Ey2 = out + 1 * (size_t)N3;
    float* Ez2 = out + 2 * (size_t)N3;
    float* Hx2 = out + 3 * (size_t)N3;
    float* Hy2 = out + 4 * (size_t)N3;
    float* Hz2 = out + 5 * (size_t)N3;

    const int block = 256;
    const int grid  = NCHUNK / block;  // 6912

    fdtd_step1<<<grid, block, 0, stream>>>(Ex, Ey, Ez, Hx, Hy, Hz, mu, Hx2, Hy2, Hz2);
    fdtd_step2<<<grid, block, 0, stream>>>(Ex, Ey, Ez, Hx2, Hy2, Hz2, eps, sigma, Ex2, Ey2, Ez2);
}

// Round 6
// 363.536 us; speedup vs baseline: 1.3391x; 1.0385x over previous
//
#include <hip/hip_runtime.h>

// 192^3 FDTD, two-pass STREAMING float4 (round 6 = round 5 + cache policy).
// R5 evidence: scalar and float4 two-pass both ~140 us combined -> memory-
// system-bound. Remaining recoverable HBM = L3 evictions of the cross-kernel
// working set (E re-read + H2 intermediate). This round:
//   - nontemporal loads on single-use streams (H, mu in step1; E-center,
//     eps, sigma in step2) so L2/L3 keep E and H2 resident instead;
//   - step2 consumes blocks in REVERSE order (L3 recency is LIFO: step1's
//     last-written H2 / last-read E are resident -> read them first);
//   - H2 loads in step2 stay NORMAL (5-7x stencil reuse lives in L1/L2);
//   - E2 stores nontemporal (never re-read).
// Math identical to the verified kernels: central differences only on the
// strict interior of all three dims; clamped addresses + per-element mask.

#define NXD 192
#define NYD 192
#define NZD 192

static constexpr int   N3     = NXD * NYD * NZD;   // 7,077,888
static constexpr int   NCHUNK = N3 / 4;            // 1,769,472
static constexpr float DTc    = 1e-12f;
static constexpr float INV2D  = 500.0f;            // 1/(2*1e-3)

static constexpr int KC = NZD / 4;                 // 48 chunks per z-row

typedef float vf4 __attribute__((ext_vector_type(4)));  // native vec for builtins

__device__ __forceinline__ int clampi(int v, int lo, int hi) {
    return v < lo ? lo : (v > hi ? hi : v);
}

__global__ __launch_bounds__(256) void fdtd_step1(
    const float* __restrict__ Ex, const float* __restrict__ Ey, const float* __restrict__ Ez,
    const float* __restrict__ Hx, const float* __restrict__ Hy, const float* __restrict__ Hz,
    const float* __restrict__ mu,
    float* __restrict__ Hx2, float* __restrict__ Hy2, float* __restrict__ Hz2)
{
    int idx4 = blockIdx.x * blockDim.x + threadIdx.x;
    if (idx4 >= NCHUNK) return;

    int kc = idx4 % KC;
    int t  = idx4 / KC;
    int j  = t % NYD;
    int i  = t / NYD;
    int k0 = kc * 4;

    int ip = clampi(i + 1, 0, NXD - 1);
    int im = clampi(i - 1, 0, NXD - 1);
    int jp = clampi(j + 1, 0, NYD - 1);
    int jm = clampi(j - 1, 0, NYD - 1);
    int km1 = (k0 > 0) ? k0 - 1 : 0;               // only consumed when masked-valid
    int kp4 = (k0 < NZD - 4) ? k0 + 4 : NZD - 1;

    int rowC  = (i  * NYD + j ) * NZD;
    int rowXp = (ip * NYD + j ) * NZD;
    int rowXm = (im * NYD + j ) * NZD;
    int rowYp = (i  * NYD + jp) * NZD;
    int rowYm = (i  * NYD + jm) * NZD;

    // E loads: stencil-reused within step1 AND re-read by step2 -> keep cached.
    vf4 ezYp = *(const vf4*)(Ez + rowYp + k0);
    vf4 ezYm = *(const vf4*)(Ez + rowYm + k0);
    vf4 exYp = *(const vf4*)(Ex + rowYp + k0);
    vf4 exYm = *(const vf4*)(Ex + rowYm + k0);
    vf4 eyXp = *(const vf4*)(Ey + rowXp + k0);
    vf4 eyXm = *(const vf4*)(Ey + rowXm + k0);
    vf4 ezXp = *(const vf4*)(Ez + rowXp + k0);
    vf4 ezXm = *(const vf4*)(Ez + rowXm + k0);
    vf4 eyC  = *(const vf4*)(Ey + rowC + k0);
    vf4 exC  = *(const vf4*)(Ex + rowC + k0);
    float ey_m1 = Ey[rowC + km1], ey_p4 = Ey[rowC + kp4];
    float ex_m1 = Ex[rowC + km1], ex_p4 = Ex[rowC + kp4];
    // H, mu: single-use streams -> nontemporal (don't pollute L2/L3).
    vf4 hxC = __builtin_nontemporal_load((const vf4*)(Hx + rowC + k0));
    vf4 hyC = __builtin_nontemporal_load((const vf4*)(Hy + rowC + k0));
    vf4 hzC = __builtin_nontemporal_load((const vf4*)(Hz + rowC + k0));
    vf4 muC = __builtin_nontemporal_load((const vf4*)(mu + rowC + k0));

    vf4 vx, vy, vz;

    bool xyok = (i >= 1) && (i <= NXD - 2) && (j >= 1) && (j <= NYD - 2);
    #pragma unroll
    for (int e = 0; e < 4; ++e) {
        int ke = k0 + e;
        bool valid = xyok && (ke >= 1) && (ke <= NZD - 2);
        float eyzm = (e == 0) ? ey_m1 : eyC[e - 1];
        float eyzp = (e == 3) ? ey_p4 : eyC[e + 1];
        float exzm = (e == 0) ? ex_m1 : exC[e - 1];
        float exzp = (e == 3) ? ex_p4 : exC[e + 1];
        float cx = valid ? ((ezYp[e] - ezYm[e]) - (eyzp - eyzm)) * INV2D : 0.0f;
        float cy = valid ? ((exzp - exzm) - (ezXp[e] - ezXm[e])) * INV2D : 0.0f;
        float cz = valid ? ((eyXp[e] - eyXm[e]) - (exYp[e] - exYm[e])) * INV2D : 0.0f;
        float f = DTc / muC[e];
        vx[e] = hxC[e] - f * cx;
        vy[e] = hyC[e] - f * cy;
        vz[e] = hzC[e] - f * cz;
    }

    // H2 is re-read by step2: keep cached (normal stores).
    *(vf4*)(Hx2 + rowC + k0) = vx;
    *(vf4*)(Hy2 + rowC + k0) = vy;
    *(vf4*)(Hz2 + rowC + k0) = vz;
}

__global__ __launch_bounds__(256) void fdtd_step2(
    const float* __restrict__ Ex, const float* __restrict__ Ey, const float* __restrict__ Ez,
    const float* __restrict__ Hx2, const float* __restrict__ Hy2, const float* __restrict__ Hz2,
    const float* __restrict__ eps, const float* __restrict__ sigma,
    float* __restrict__ Ex2, float* __restrict__ Ey2, float* __restrict__ Ez2)
{
    // Reverse block order: consume the L3-resident tail of step1's stream first.
    int bid  = (int)gridDim.x - 1 - (int)blockIdx.x;
    int idx4 = bid * (int)blockDim.x + (int)threadIdx.x;
    if (idx4 >= NCHUNK) return;

    int kc = idx4 % KC;
    int t  = idx4 / KC;
    int j  = t % NYD;
    int i  = t / NYD;
    int k0 = kc * 4;

    int ip = clampi(i + 1, 0, NXD - 1);
    int im = clampi(i - 1, 0, NXD - 1);
    int jp = clampi(j + 1, 0, NYD - 1);
    int jm = clampi(j - 1, 0, NYD - 1);
    int km1 = (k0 > 0) ? k0 - 1 : 0;
    int kp4 = (k0 < NZD - 4) ? k0 + 4 : NZD - 1;

    int rowC  = (i  * NYD + j ) * NZD;
    int rowXp = (ip * NYD + j ) * NZD;
    int rowXm = (im * NYD + j ) * NZD;
    int rowYp = (i  * NYD + jp) * NZD;
    int rowYm = (i  * NYD + jm) * NZD;

    // H2: stencil-reused across threads/blocks -> NORMAL loads (keep L1/L2 hits).
    vf4 hzYp = *(const vf4*)(Hz2 + rowYp + k0);
    vf4 hzYm = *(const vf4*)(Hz2 + rowYm + k0);
    vf4 hxYp = *(const vf4*)(Hx2 + rowYp + k0);
    vf4 hxYm = *(const vf4*)(Hx2 + rowYm + k0);
    vf4 hyXp = *(const vf4*)(Hy2 + rowXp + k0);
    vf4 hyXm = *(const vf4*)(Hy2 + rowXm + k0);
    vf4 hzXp = *(const vf4*)(Hz2 + rowXp + k0);
    vf4 hzXm = *(const vf4*)(Hz2 + rowXm + k0);
    vf4 hyC  = *(const vf4*)(Hy2 + rowC + k0);
    vf4 hxC  = *(const vf4*)(Hx2 + rowC + k0);
    float hy_m1 = Hy2[rowC + km1], hy_p4 = Hy2[rowC + kp4];
    float hx_m1 = Hx2[rowC + km1], hx_p4 = Hx2[rowC + kp4];
    // E center, eps, sigma: last/single use -> nontemporal.
    vf4 exC  = __builtin_nontemporal_load((const vf4*)(Ex + rowC + k0));
    vf4 eyC  = __builtin_nontemporal_load((const vf4*)(Ey + rowC + k0));
    vf4 ezC  = __builtin_nontemporal_load((const vf4*)(Ez + rowC + k0));
    vf4 epsC = __builtin_nontemporal_load((const vf4*)(eps + rowC + k0));
    vf4 sigC = __builtin_nontemporal_load((const vf4*)(sigma + rowC + k0));

    vf4 ex2, ey2, ez2;

    bool xyok = (i >= 1) && (i <= NXD - 2) && (j >= 1) && (j <= NYD - 2);
    #pragma unroll
    for (int e = 0; e < 4; ++e) {
        int ke = k0 + e;
        bool valid = xyok && (ke >= 1) && (ke <= NZD - 2);
        float hyzm = (e == 0) ? hy_m1 : hyC[e - 1];
        float hyzp = (e == 3) ? hy_p4 : hyC[e + 1];
        float hxzm = (e == 0) ? hx_m1 : hxC[e - 1];
        float hxzp = (e == 3) ? hx_p4 : hxC[e + 1];
        float cx = valid ? ((hzYp[e] - hzYm[e]) - (hyzp - hyzm)) * INV2D : 0.0f;
        float cy = valid ? ((hxzp - hxzm) - (hzXp[e] - hzXm[e])) * INV2D : 0.0f;
        float cz = valid ? ((hyXp[e] - hyXm[e]) - (hxYp[e] - hxYm[e])) * INV2D : 0.0f;

        float ee = epsC[e];
        float ss = sigC[e];
        float half_sdt_over_e = ss * DTc / (2.0f * ee);
        float Ap = 1.0f + half_sdt_over_e;
        float Am = 1.0f - half_sdt_over_e;
        float coefE = Am / Ap;
        float coefC = DTc / (ee * Ap);
        ex2[e] = coefE * exC[e] + coefC * cx;
        ey2[e] = coefE * eyC[e] + coefC * cy;
        ez2[e] = coefE * ezC[e] + coefC * cz;
    }

    // E2 is never re-read: nontemporal stores.
    __builtin_nontemporal_store(ex2, (vf4*)(Ex2 + rowC + k0));
    __builtin_nontemporal_store(ey2, (vf4*)(Ey2 + rowC + k0));
    __builtin_nontemporal_store(ez2, (vf4*)(Ez2 + rowC + k0));
}

extern "C" void kernel_launch(void* const* d_in, const int* in_sizes, int n_in,
                              void* d_out, int out_size, void* d_ws, size_t ws_size,
                              hipStream_t stream)
{
    // setup_inputs order: Ex, Ey, Ez, Hx, Hy, Hz, eps, mu, sigma
    const float* Ex    = (const float*)d_in[0];
    const float* Ey    = (const float*)d_in[1];
    const float* Ez    = (const float*)d_in[2];
    const float* Hx    = (const float*)d_in[3];
    const float* Hy    = (const float*)d_in[4];
    const float* Hz    = (const float*)d_in[5];
    const float* eps   = (const float*)d_in[6];
    const float* mu    = (const float*)d_in[7];
    const float* sigma = (const float*)d_in[8];

    // outputs concatenated flat in return order: ex2, ey2, ez2, hx2, hy2, hz2
    float* out = (float*)d_out;
    float* Ex2 = out + 0 * (size_t)N3;
    float* Ey2 = out + 1 * (size_t)N3;
    float* Ez2 = out + 2 * (size_t)N3;
    float* Hx2 = out + 3 * (size_t)N3;
    float* Hy2 = out + 4 * (size_t)N3;
    float* Hz2 = out + 5 * (size_t)N3;

    const int block = 256;
    const int grid  = NCHUNK / block;  // 6912

    fdtd_step1<<<grid, block, 0, stream>>>(Ex, Ey, Ez, Hx, Hy, Hz, mu, Hx2, Hy2, Hz2);
    fdtd_step2<<<grid, block, 0, stream>>>(Ex, Ey, Ez, Hx2, Hy2, Hz2, eps, sigma, Ex2, Ey2, Ez2);
}